// Round 7
// baseline (1522.219 us; speedup 1.0000x reference)
//
#include <hip/hip_runtime.h>
#include <hip/hip_bf16.h>
#include <float.h>

#define N_NODES 100000
#define N_EDGES 1600000
#define HEADS 4
#define OUT_F 32
#define NEG_SLOPE 0.2f
#define EXP_SHIFT 8.0f

#define NSLICE 12500 // nodes per coarse bucket (8 * 12500 = 100000)
#define NB2 98       // bins per bucket (98 * 128 = 12544 >= 12500)
#define BINSZ 128    // nodes per bin
#define BCAP 210000  // per-bucket capacity (mean 200000, +24 sigma)
#define BINCAP 2688  // per-bin capacity (mean 2048, +14 sigma)
#define C2BLK 16     // classify2 blocks per bucket
#define C2STAGE 13184

typedef __attribute__((ext_vector_type(8))) short short8;
typedef __attribute__((ext_vector_type(4))) float f32x4;
typedef __attribute__((ext_vector_type(4))) int i32x4;

__device__ __forceinline__ unsigned short f2bf(float f) {
    unsigned int u = __float_as_uint(f);
    u += 0x7fff + ((u >> 16) & 1);   // round-to-nearest-even
    return (unsigned short)(u >> 16);
}

// order-preserving float->u32 encode (for LDS atomicMax); raw 0 reserved as -inf
__device__ __forceinline__ unsigned fenc(float f) {
    unsigned u = __float_as_uint(f);
    return u ^ ((unsigned)(((int)u) >> 31) | 0x80000000u);
}
__device__ __forceinline__ float fdec(unsigned u) {
    return (u & 0x80000000u) ? __uint_as_float(u ^ 0x80000000u) : __uint_as_float(~u);
}

// ---------------- prep: transpose W -> Wt (bf16)
__global__ __launch_bounds__(256) void k_prep(const float* __restrict__ W,
                                              unsigned short* __restrict__ Wt) {
    int idx = blockIdx.x * 256 + threadIdx.x;   // 0..8191
    int n = idx & 127, k2 = idx >> 7;           // k2 in 0..63
    float w0 = W[(size_t)(2 * k2) * 128 + n];
    float w1 = W[(size_t)(2 * k2 + 1) * 128 + n];
    *(ushort2*)&Wt[(size_t)n * 128 + 2 * k2] = make_ushort2(f2bf(w0), f2bf(w1));
}

// ---------------- classify1: one pass over edges -> 8 coarse buckets of packed
// records (src | dstLocal<<17). Per-block appends are ~512B-dense per bucket.
__global__ __launch_bounds__(256) void k_classify(const int* __restrict__ ei,
                                                  int* __restrict__ bcnt,
                                                  int* __restrict__ buck) {
    __shared__ int lh[8];
    __shared__ int lcur[8];
    int tid = threadIdx.x;
    if (tid < 8) lh[tid] = 0;
    __syncthreads();
    int i4 = blockIdx.x * 256 + tid;
    bool valid = i4 < N_EDGES / 4;
    int g0 = 0, g1 = 0, g2 = 0, g3 = 0, r0 = 0, r1 = 0, r2 = 0, r3 = 0;
    if (valid) {
        i32x4 s = ((const i32x4*)ei)[i4];
        i32x4 d = ((const i32x4*)(ei + N_EDGES))[i4];
        g0 = d.x / NSLICE; r0 = s.x | ((d.x - g0 * NSLICE) << 17);
        g1 = d.y / NSLICE; r1 = s.y | ((d.y - g1 * NSLICE) << 17);
        g2 = d.z / NSLICE; r2 = s.z | ((d.z - g2 * NSLICE) << 17);
        g3 = d.w / NSLICE; r3 = s.w | ((d.w - g3 * NSLICE) << 17);
        atomicAdd(&lh[g0], 1);
        atomicAdd(&lh[g1], 1);
        atomicAdd(&lh[g2], 1);
        atomicAdd(&lh[g3], 1);
    }
    __syncthreads();
    if (tid < 8) lcur[tid] = atomicAdd(&bcnt[tid], lh[tid]);
    __syncthreads();
    if (valid) {
        int p;
        p = atomicAdd(&lcur[g0], 1); buck[(size_t)g0 * BCAP + p] = r0;
        p = atomicAdd(&lcur[g1], 1); buck[(size_t)g1 * BCAP + p] = r1;
        p = atomicAdd(&lcur[g2], 1); buck[(size_t)g2 * BCAP + p] = r2;
        p = atomicAdd(&lcur[g3], 1); buck[(size_t)g3 * BCAP + p] = r3;
    }
}

// ---------------- classify2: bucket -> 98 bins of 128 nodes each. Stage chunk in
// LDS, LDS histogram, one global atomicAdd per (block,bin), dense appends.
// Record repacked to (src | rInBin<<17), rInBin in 0..127.
__global__ __launch_bounds__(256) void k_classify2(const int* __restrict__ bcnt,
                                                   const int* __restrict__ buck,
                                                   int* __restrict__ bincnt2,
                                                   int* __restrict__ buck2) {
    __shared__ int stage[C2STAGE];
    __shared__ int lh[NB2];
    __shared__ int lcur[NB2];
    int g = blockIdx.x >> 4, j = blockIdx.x & 15;
    int tid = threadIdx.x;
    for (int i = tid; i < NB2; i += 256) lh[i] = 0;
    __syncthreads();
    int n = bcnt[g]; if (n > BCAP) n = BCAP;
    int chunk = (n + C2BLK - 1) / C2BLK;
    int lo = j * chunk;
    int hi = lo + chunk; if (hi > n) hi = n;
    int cnt = hi - lo; if (cnt < 0) cnt = 0;
    const int* bk = buck + (size_t)g * BCAP + lo;
    for (int i = tid; i < cnt; i += 256) {
        int rec = bk[i];
        stage[i] = rec;
        atomicAdd(&lh[(rec >> 17) >> 7], 1);
    }
    __syncthreads();
    for (int b = tid; b < NB2; b += 256)
        lcur[b] = atomicAdd(&bincnt2[g * NB2 + b], lh[b]);
    __syncthreads();
    for (int i = tid; i < cnt; i += 256) {
        int rec = stage[i];
        int b = (rec >> 17) >> 7;
        int p = atomicAdd(&lcur[b], 1);
        if (p < BINCAP)
            buck2[(size_t)(g * NB2 + b) * BINCAP + p] =
                (rec & 0x1FFFF) | (((rec >> 17) & 127) << 17);
    }
}

// ---------------- GEMM: Whb(bf16) = h @ W; also s_srcE (order-encoded) + s_dst
__global__ __launch_bounds__(512) void k_gemm(const float* __restrict__ hp,
                                              const unsigned short* __restrict__ Wt,
                                              const float* __restrict__ av,
                                              unsigned short* __restrict__ Whb,
                                              unsigned* __restrict__ sE,
                                              float* __restrict__ s_dst) {
    __shared__ short wsB[128][136];
    int tid = threadIdx.x;
    int rowBase = blockIdx.x * 128;

    const short8* Wt8 = (const short8*)Wt;
#pragma unroll
    for (int i = 0; i < 4; i++) {
        int idx = tid + 512 * i;          // 0..2047
        int n = idx >> 4, ch = idx & 15;
        *(short8*)&wsB[n][ch * 8] = Wt8[idx];
    }
    __syncthreads();

    int lane = tid & 63;
    int wv = tid >> 6;                    // 0..7
    int l16 = lane & 15, quad = lane >> 4;

    int arow = rowBase + wv * 16 + l16;
    bool valid = arow < N_NODES;
    const float* hrow = hp + (size_t)arow * 128;
    short8 afr[4];
#pragma unroll
    for (int k4 = 0; k4 < 4; k4++) {
        float4 u0 = valid ? *(const float4*)&hrow[k4 * 32 + quad * 8]
                          : make_float4(0.f, 0.f, 0.f, 0.f);
        float4 u1 = valid ? *(const float4*)&hrow[k4 * 32 + quad * 8 + 4]
                          : make_float4(0.f, 0.f, 0.f, 0.f);
        afr[k4] = (short8){(short)f2bf(u0.x), (short)f2bf(u0.y),
                           (short)f2bf(u0.z), (short)f2bf(u0.w),
                           (short)f2bf(u1.x), (short)f2bf(u1.y),
                           (short)f2bf(u1.z), (short)f2bf(u1.w)};
    }

    f32x4 acc[8];
#pragma unroll
    for (int nt = 0; nt < 8; nt++) {
        acc[nt] = (f32x4){0.f, 0.f, 0.f, 0.f};
#pragma unroll
        for (int k4 = 0; k4 < 4; k4++) {
            short8 bfr = *(const short8*)&wsB[nt * 16 + l16][k4 * 32 + quad * 8];
            acc[nt] = __builtin_amdgcn_mfma_f32_16x16x32_bf16(afr[k4], bfr, acc[nt], 0, 0, 0);
        }
    }

    int row0 = rowBase + wv * 16 + quad * 4;
#pragma unroll
    for (int r = 0; r < 4; r++) {
        int row = row0 + r;
        if (row < N_NODES) {
#pragma unroll
            for (int nt = 0; nt < 8; nt++)
                Whb[(size_t)row * 128 + nt * 16 + l16] = f2bf(acc[nt][r]);
        }
    }

    float ps[4][4], pd[4][4];
#pragma unroll
    for (int h = 0; h < 4; h++) {
        float a0s = av[h * 64 + l16];
        float a1s = av[h * 64 + 16 + l16];
        float a0d = av[h * 64 + 32 + l16];
        float a1d = av[h * 64 + 48 + l16];
#pragma unroll
        for (int r = 0; r < 4; r++) {
            ps[h][r] = acc[2 * h][r] * a0s + acc[2 * h + 1][r] * a1s;
            pd[h][r] = acc[2 * h][r] * a0d + acc[2 * h + 1][r] * a1d;
        }
    }
#pragma unroll
    for (int h = 0; h < 4; h++)
#pragma unroll
        for (int r = 0; r < 4; r++) {
#pragma unroll
            for (int off = 1; off < 16; off <<= 1) {
                ps[h][r] += __shfl_xor(ps[h][r], off);
                pd[h][r] += __shfl_xor(pd[h][r], off);
            }
        }
    if (l16 < 4) {
#pragma unroll
        for (int r = 0; r < 4; r++) {
            int row = row0 + r;
            if (row < N_NODES) {
                float vs = (l16 == 0) ? ps[0][r] : (l16 == 1) ? ps[1][r]
                         : (l16 == 2) ? ps[2][r] : ps[3][r];
                float vd = (l16 == 0) ? pd[0][r] : (l16 == 1) ? pd[1][r]
                         : (l16 == 2) ? pd[2][r] : pd[3][r];
                sE[row * 4 + l16] = fenc(vs);
                s_dst[row * 4 + l16] = vd;
            }
        }
    }
}

// ---------------- max: per-bin segment max via LDS atomicMax on encoded u32;
// then expv + partial softmax denominator S. leaky_relu monotone => max commutes.
__global__ __launch_bounds__(256) void k_max(const int* __restrict__ bincnt2,
                                             const int* __restrict__ buck2,
                                             const unsigned* __restrict__ sE,
                                             const float* __restrict__ s_dst,
                                             float* __restrict__ expv,
                                             float* __restrict__ S) {
    __shared__ unsigned mx[BINSZ][4];
    __shared__ float sred[4][4];
    int bin = blockIdx.x;
    int g = bin / NB2, b = bin - g * NB2;
    int tid = threadIdx.x;
    mx[tid >> 2][tid & 3] = 0u;              // raw 0 == -inf sentinel
    mx[(tid >> 2) + 64][tid & 3] = 0u;
    __syncthreads();
    int cntb = bincnt2[bin]; if (cntb > BINCAP) cntb = BINCAP;
    const int* bk = buck2 + (size_t)bin * BINCAP;
    for (int i = tid; i < cntb; i += 256) {
        int rec = bk[i];
        int src = rec & 0x1FFFF;
        int r = rec >> 17;
        uint4 e = ((const uint4*)sE)[src];
        atomicMax(&mx[r][0], e.x);
        atomicMax(&mx[r][1], e.y);
        atomicMax(&mx[r][2], e.z);
        atomicMax(&mx[r][3], e.w);
    }
    __syncthreads();
    float4 e4 = make_float4(0.f, 0.f, 0.f, 0.f);
    int rel = b * BINSZ + tid;
    int node = g * NSLICE + rel;
    if (tid < BINSZ && rel < NSLICE) {
        unsigned r0 = mx[tid][0], r1 = mx[tid][1], r2 = mx[tid][2], r3 = mx[tid][3];
        float m0 = r0 ? fdec(r0) : -3e38f;
        float m1 = r1 ? fdec(r1) : -3e38f;
        float m2 = r2 ? fdec(r2) : -3e38f;
        float m3 = r3 ? fdec(r3) : -3e38f;
        float4 d = ((const float4*)s_dst)[node];
        float x;
        x = m0 + d.x; x = x > 0.f ? x : NEG_SLOPE * x; e4.x = __expf(x - EXP_SHIFT);
        x = m1 + d.y; x = x > 0.f ? x : NEG_SLOPE * x; e4.y = __expf(x - EXP_SHIFT);
        x = m2 + d.z; x = x > 0.f ? x : NEG_SLOPE * x; e4.z = __expf(x - EXP_SHIFT);
        x = m3 + d.w; x = x > 0.f ? x : NEG_SLOPE * x; e4.w = __expf(x - EXP_SHIFT);
        ((float4*)expv)[node] = e4;
    }
    int lane = tid & 63, wv = tid >> 6;
#pragma unroll
    for (int off = 32; off; off >>= 1) {
        e4.x += __shfl_xor(e4.x, off);
        e4.y += __shfl_xor(e4.y, off);
        e4.z += __shfl_xor(e4.z, off);
        e4.w += __shfl_xor(e4.w, off);
    }
    if (lane == 0) { sred[wv][0] = e4.x; sred[wv][1] = e4.y; sred[wv][2] = e4.z; sred[wv][3] = e4.w; }
    __syncthreads();
    if (tid < 4) {
        float s = sred[0][tid] + sred[1][tid] + sred[2][tid] + sred[3][tid];
        atomicAdd(&S[tid], s);
    }
}

// ---------------- sum: per-bin segment sum of Whb rows into LDS f32 accumulators
// (no per-node edge lists!), then scale by attn = expv/S and write out coalesced.
__global__ __launch_bounds__(512) void k_sum(const int* __restrict__ bincnt2,
                                             const int* __restrict__ buck2,
                                             const unsigned* __restrict__ Whb32,
                                             const float* __restrict__ expv,
                                             const float* __restrict__ S,
                                             float* __restrict__ out) {
    __shared__ float acc[BINSZ][2][64];   // 64 KB; [r][half][lane]: col = 2*lane+half
    __shared__ int srec[BINCAP];          // 10.75 KB
    __shared__ float Sl[4];
    int bin = blockIdx.x;
    int g = bin / NB2, b = bin - g * NB2;
    int tid = threadIdx.x;
    float* az = &acc[0][0][0];
    for (int i = tid; i < BINSZ * 128; i += 512) az[i] = 0.f;
    if (tid < 4) Sl[tid] = S[tid];
    int cntb = bincnt2[bin]; if (cntb > BINCAP) cntb = BINCAP;
    const int* bk = buck2 + (size_t)bin * BINCAP;
    for (int i = tid; i < cntb; i += 512) srec[i] = bk[i];
    __syncthreads();

    int lane = tid & 63, w = tid >> 6;
    const unsigned* Wl = Whb32 + lane;
    int i = w;
    for (; i + 24 < cntb; i += 32) {
        int r0 = srec[i], r1 = srec[i + 8], r2 = srec[i + 16], r3 = srec[i + 24];
        unsigned v0 = Wl[(size_t)(r0 & 0x1FFFF) * 64];
        unsigned v1 = Wl[(size_t)(r1 & 0x1FFFF) * 64];
        unsigned v2 = Wl[(size_t)(r2 & 0x1FFFF) * 64];
        unsigned v3 = Wl[(size_t)(r3 & 0x1FFFF) * 64];
        atomicAdd(&acc[r0 >> 17][0][lane], __uint_as_float(v0 << 16));
        atomicAdd(&acc[r0 >> 17][1][lane], __uint_as_float(v0 & 0xffff0000u));
        atomicAdd(&acc[r1 >> 17][0][lane], __uint_as_float(v1 << 16));
        atomicAdd(&acc[r1 >> 17][1][lane], __uint_as_float(v1 & 0xffff0000u));
        atomicAdd(&acc[r2 >> 17][0][lane], __uint_as_float(v2 << 16));
        atomicAdd(&acc[r2 >> 17][1][lane], __uint_as_float(v2 & 0xffff0000u));
        atomicAdd(&acc[r3 >> 17][0][lane], __uint_as_float(v3 << 16));
        atomicAdd(&acc[r3 >> 17][1][lane], __uint_as_float(v3 & 0xffff0000u));
    }
    for (; i < cntb; i += 8) {
        int r0 = srec[i];
        unsigned v0 = Wl[(size_t)(r0 & 0x1FFFF) * 64];
        atomicAdd(&acc[r0 >> 17][0][lane], __uint_as_float(v0 << 16));
        atomicAdd(&acc[r0 >> 17][1][lane], __uint_as_float(v0 & 0xffff0000u));
    }
    __syncthreads();

    // writeout: 512 threads = 128 nodes x 4 quarters (quarter == head: 32 cols)
    int n = tid >> 2, q = tid & 3;
    int rel = b * BINSZ + n;
    int node = g * NSLICE + rel;
    if (rel < NSLICE) {
        float attn = expv[node * 4 + q] / Sl[q];
        float* orow = out + (size_t)node * 128 + q * 32;
#pragma unroll
        for (int j4 = 0; j4 < 8; j4++) {
            int c0 = q * 32 + j4 * 4;
            float4 v;
            v.x = acc[n][c0 & 1][c0 >> 1] * attn;
            v.y = acc[n][(c0 + 1) & 1][(c0 + 1) >> 1] * attn;
            v.z = acc[n][(c0 + 2) & 1][(c0 + 2) >> 1] * attn;
            v.w = acc[n][(c0 + 3) & 1][(c0 + 3) >> 1] * attn;
            *(float4*)&orow[j4 * 4] = v;
        }
    }
}

extern "C" void kernel_launch(void* const* d_in, const int* in_sizes, int n_in,
                              void* d_out, int out_size, void* d_ws, size_t ws_size,
                              hipStream_t stream) {
    const float* h  = (const float*)d_in[0];
    const int*   ei = (const int*)d_in[1];
    const float* W  = (const float*)d_in[2];
    const float* a  = (const float*)d_in[3];
    float* out = (float*)d_out;

    char* ws = (char*)d_ws;
    unsigned short* Whb = (unsigned short*)(ws);     // 25,600,256
    unsigned* sE   = (unsigned*)(ws + 25600256);     //  1,600,000
    float* s_dst   = (float*)   (ws + 27200256);     //  1,600,000
    float* expv    = (float*)   (ws + 28800256);     //  1,600,000
    float* S       = (float*)   (ws + 30400256);     //         16 ┐ one
    int*   bcnt    = (int*)     (ws + 30400272);     //         32 │ memset
    int*   bincnt2 = (int*)     (ws + 30400304);     //      3,136 ┘
    int*   buck    = (int*)     (ws + 30403440);     //  6,720,000 (8 * 210000 * 4)
    int*   buck2   = (int*)     (ws + 37123440);     //  8,429,568 (784 * 2688 * 4)
    unsigned short* Wt = (unsigned short*)(ws + 45553008); // 32,768
                                                     // total 45,585,776

    hipMemsetAsync(S, 0, 3184, stream);              // S + bcnt + bincnt2
    k_prep<<<32, 256, 0, stream>>>(W, Wt);
    k_classify<<<(N_EDGES / 4 + 255) / 256, 256, 0, stream>>>(ei, bcnt, buck);
    k_classify2<<<128, 256, 0, stream>>>(bcnt, buck, bincnt2, buck2);
    k_gemm<<<782, 512, 0, stream>>>(h, Wt, a, Whb, sE, s_dst);
    k_max<<<8 * NB2, 256, 0, stream>>>(bincnt2, buck2, sE, s_dst, expv, S);
    k_sum<<<8 * NB2, 512, 0, stream>>>(bincnt2, buck2, (const unsigned*)Whb, expv, S, out);
}

// Round 9
// 265.178 us; speedup vs baseline: 5.7404x; 5.7404x over previous
//
#include <hip/hip_runtime.h>
#include <hip/hip_bf16.h>
#include <float.h>

#define N_NODES 100000
#define N_EDGES 1600000
#define HEADS 4
#define OUT_F 32
#define NEG_SLOPE 0.2f
#define EXP_SHIFT 8.0f

#define NSLICE 12500 // nodes per coarse bucket (8 * 12500 = 100000)
#define NBIN 98      // bins per bucket (98 * 128 = 12544 >= 12500)
#define BCAP 210000  // per-bucket capacity (mean 200000, +24 sigma)
#define BINCAP 2688  // per-bin real-record cap (mean 2048, +14 sigma)
#define BINST 3072   // esrc stride per bin (BINCAP + 128*3 pad headroom)

typedef __attribute__((ext_vector_type(8))) short short8;
typedef __attribute__((ext_vector_type(4))) float f32x4;
typedef __attribute__((ext_vector_type(4))) int i32x4;

__device__ __forceinline__ unsigned short f2bf(float f) {
    unsigned int u = __float_as_uint(f);
    u += 0x7fff + ((u >> 16) & 1);   // round-to-nearest-even
    return (unsigned short)(u >> 16);
}

// ---------------- prep: transpose W -> Wt (bf16); s_src sentinel row (-1e30)
__global__ __launch_bounds__(256) void k_prep(const float* __restrict__ W,
                                              unsigned short* __restrict__ Wt,
                                              float* __restrict__ s_src) {
    int idx = blockIdx.x * 256 + threadIdx.x;   // 0..8191
    int n = idx & 127, k2 = idx >> 7;           // k2 in 0..63
    float w0 = W[(size_t)(2 * k2) * 128 + n];
    float w1 = W[(size_t)(2 * k2 + 1) * 128 + n];
    *(ushort2*)&Wt[(size_t)n * 128 + 2 * k2] = make_ushort2(f2bf(w0), f2bf(w1));
    if (idx < 4) s_src[N_NODES * 4 + idx] = -1e30f;   // pad-node sentinel for max
}

// ---------------- classify: one dense pass over edges -> 8 coarse buckets of
// packed records (src | dstLocal<<17). Per-block appends are dense (full lines).
__global__ __launch_bounds__(256) void k_classify(const int* __restrict__ ei,
                                                  int* __restrict__ bcnt,
                                                  int* __restrict__ buck) {
    __shared__ int lh[8];
    __shared__ int lcur[8];
    int tid = threadIdx.x;
    if (tid < 8) lh[tid] = 0;
    __syncthreads();
    int i4 = blockIdx.x * 256 + tid;
    bool valid = i4 < N_EDGES / 4;
    int g0 = 0, g1 = 0, g2 = 0, g3 = 0, r0 = 0, r1 = 0, r2 = 0, r3 = 0;
    if (valid) {
        i32x4 s = ((const i32x4*)ei)[i4];
        i32x4 d = ((const i32x4*)(ei + N_EDGES))[i4];
        g0 = d.x / NSLICE; r0 = s.x | ((d.x - g0 * NSLICE) << 17);
        g1 = d.y / NSLICE; r1 = s.y | ((d.y - g1 * NSLICE) << 17);
        g2 = d.z / NSLICE; r2 = s.z | ((d.z - g2 * NSLICE) << 17);
        g3 = d.w / NSLICE; r3 = s.w | ((d.w - g3 * NSLICE) << 17);
        atomicAdd(&lh[g0], 1);
        atomicAdd(&lh[g1], 1);
        atomicAdd(&lh[g2], 1);
        atomicAdd(&lh[g3], 1);
    }
    __syncthreads();
    if (tid < 8) lcur[tid] = atomicAdd(&bcnt[tid], lh[tid]);
    __syncthreads();
    if (valid) {
        int p;
        p = atomicAdd(&lcur[g0], 1); if (p < BCAP) buck[(size_t)g0 * BCAP + p] = r0;
        p = atomicAdd(&lcur[g1], 1); if (p < BCAP) buck[(size_t)g1 * BCAP + p] = r1;
        p = atomicAdd(&lcur[g2], 1); if (p < BCAP) buck[(size_t)g2 * BCAP + p] = r2;
        p = atomicAdd(&lcur[g3], 1); if (p < BCAP) buck[(size_t)g3 * BCAP + p] = r3;
    }
}

// ---------------- GEMM: Whb(bf16, rows 0..N_NODES incl zero pad row) = h @ W
__global__ __launch_bounds__(512) void k_gemm(const float* __restrict__ hp,
                                              const unsigned short* __restrict__ Wt,
                                              const float* __restrict__ av,
                                              unsigned short* __restrict__ Whb,
                                              float* __restrict__ s_src,
                                              float* __restrict__ s_dst) {
    __shared__ short wsB[128][136];
    int tid = threadIdx.x;
    int rowBase = blockIdx.x * 128;

    const short8* Wt8 = (const short8*)Wt;
#pragma unroll
    for (int i = 0; i < 4; i++) {
        int idx = tid + 512 * i;          // 0..2047
        int n = idx >> 4, ch = idx & 15;
        *(short8*)&wsB[n][ch * 8] = Wt8[idx];
    }
    __syncthreads();

    int lane = tid & 63;
    int wv = tid >> 6;                    // 0..7
    int l16 = lane & 15, quad = lane >> 4;

    int arow = rowBase + wv * 16 + l16;
    bool valid = arow < N_NODES;
    const float* hrow = hp + (size_t)arow * 128;
    short8 afr[4];
#pragma unroll
    for (int k4 = 0; k4 < 4; k4++) {
        float4 u0 = valid ? *(const float4*)&hrow[k4 * 32 + quad * 8]
                          : make_float4(0.f, 0.f, 0.f, 0.f);
        float4 u1 = valid ? *(const float4*)&hrow[k4 * 32 + quad * 8 + 4]
                          : make_float4(0.f, 0.f, 0.f, 0.f);
        afr[k4] = (short8){(short)f2bf(u0.x), (short)f2bf(u0.y),
                           (short)f2bf(u0.z), (short)f2bf(u0.w),
                           (short)f2bf(u1.x), (short)f2bf(u1.y),
                           (short)f2bf(u1.z), (short)f2bf(u1.w)};
    }

    f32x4 acc[8];
#pragma unroll
    for (int nt = 0; nt < 8; nt++) {
        acc[nt] = (f32x4){0.f, 0.f, 0.f, 0.f};
#pragma unroll
        for (int k4 = 0; k4 < 4; k4++) {
            short8 bfr = *(const short8*)&wsB[nt * 16 + l16][k4 * 32 + quad * 8];
            acc[nt] = __builtin_amdgcn_mfma_f32_16x16x32_bf16(afr[k4], bfr, acc[nt], 0, 0, 0);
        }
    }

    int row0 = rowBase + wv * 16 + quad * 4;
#pragma unroll
    for (int r = 0; r < 4; r++) {
        int row = row0 + r;
        if (row <= N_NODES) {             // row N_NODES = zero pad row (acc==0 there)
#pragma unroll
            for (int nt = 0; nt < 8; nt++)
                Whb[(size_t)row * 128 + nt * 16 + l16] = f2bf(acc[nt][r]);
        }
    }

    float ps[4][4], pd[4][4];
#pragma unroll
    for (int h = 0; h < 4; h++) {
        float a0s = av[h * 64 + l16];
        float a1s = av[h * 64 + 16 + l16];
        float a0d = av[h * 64 + 32 + l16];
        float a1d = av[h * 64 + 48 + l16];
#pragma unroll
        for (int r = 0; r < 4; r++) {
            ps[h][r] = acc[2 * h][r] * a0s + acc[2 * h + 1][r] * a1s;
            pd[h][r] = acc[2 * h][r] * a0d + acc[2 * h + 1][r] * a1d;
        }
    }
#pragma unroll
    for (int h = 0; h < 4; h++)
#pragma unroll
        for (int r = 0; r < 4; r++) {
#pragma unroll
            for (int off = 1; off < 16; off <<= 1) {
                ps[h][r] += __shfl_xor(ps[h][r], off);
                pd[h][r] += __shfl_xor(pd[h][r], off);
            }
        }
    if (l16 < 4) {
#pragma unroll
        for (int r = 0; r < 4; r++) {
            int row = row0 + r;
            if (row < N_NODES) {
                float vs = (l16 == 0) ? ps[0][r] : (l16 == 1) ? ps[1][r]
                         : (l16 == 2) ? ps[2][r] : ps[3][r];
                float vd = (l16 == 0) ? pd[0][r] : (l16 == 1) ? pd[1][r]
                         : (l16 == 2) ? pd[2][r] : pd[3][r];
                s_src[row * 4 + l16] = vs;
                s_dst[row * 4 + l16] = vd;
            }
        }
    }
}

// ---------------- bin: one block per 128-node bin. blockIdx = sub*8 + g, so the
// 98 blocks of bucket g sit on XCD g (round-robin) and stream the SAME 0.84 MB
// bucket out of the local L2. Filter-append bin's records to LDS + histogram,
// scan(x4-pad), LDS sort, coalesced int4 esrc writeout, inline max/expv/partial S.
// No scattered global stores anywhere.
__global__ __launch_bounds__(512) void k_bin(const int* __restrict__ bcnt,
                                             const int* __restrict__ buck,
                                             const float* __restrict__ s_src,
                                             const float* __restrict__ s_dst,
                                             int* __restrict__ esrc,
                                             int* __restrict__ cnt,
                                             int* __restrict__ start,
                                             float* __restrict__ expv,
                                             float* __restrict__ S) {
    __shared__ int stage[BINCAP];
    __shared__ int stage2[BINST];
    __shared__ int lh[128], lbase[128], lcur[128];
    __shared__ int lN;
    __shared__ int wtot2[2];
    __shared__ float sred[8][4];
    int g = blockIdx.x & 7;
    int sub = blockIdx.x >> 3;            // 0..97
    int tid = threadIdx.x;
    if (tid < 128) lh[tid] = 0;
    if (tid == 0) lN = 0;
    __syncthreads();

    int n = bcnt[g]; if (n > BCAP) n = BCAP;
    const int* bk = buck + (size_t)g * BCAP;
    const i32x4* bk4 = (const i32x4*)bk;
    int n4 = n >> 2;
    // ---- filter-append + histogram
    for (int i = tid; i < n4; i += 512) {
        i32x4 r = bk4[i];
#pragma unroll
        for (int j = 0; j < 4; j++) {
            int rec = (j == 0) ? r.x : (j == 1) ? r.y : (j == 2) ? r.z : r.w;
            int rb = rec >> 17;           // dstLocal 0..12499
            if ((rb >> 7) == sub) {
                int p = atomicAdd(&lN, 1);
                if (p < BINCAP) { stage[p] = rec; atomicAdd(&lh[rb & 127], 1); }
            }
        }
    }
    for (int i = (n4 << 2) + tid; i < n; i += 512) {
        int rec = bk[i];
        int rb = rec >> 17;
        if ((rb >> 7) == sub) {
            int p = atomicAdd(&lN, 1);
            if (p < BINCAP) { stage[p] = rec; atomicAdd(&lh[rb & 127], 1); }
        }
    }
    __syncthreads();
    int total = lN < BINCAP ? lN : BINCAP;

    // ---- scan of x4-padded counts (tid<128, 2 waves)
    int val = 0, padded = 0, rel = 0;
    if (tid < 128) {
        val = lh[tid];
        padded = (val + 3) & ~3;
        int v = padded;
        int lane = tid & 63;
#pragma unroll
        for (int off = 1; off < 64; off <<= 1) {
            int t = __shfl_up(v, off);
            if (lane >= off) v += t;
        }
        if (lane == 63) wtot2[tid >> 6] = v;
        rel = v - padded;
    }
    __syncthreads();
    int base = blockIdx.x * BINST;
    if (tid < 128) {
        if (tid >= 64) rel += wtot2[0];
        int nrel = (sub << 7) + tid;
        int node = g * NSLICE + nrel;
        if (nrel < NSLICE) { cnt[node] = padded; start[node] = base + rel; }
        lbase[tid] = rel;
        lcur[tid] = rel;
    }
    __syncthreads();
    // ---- sort into stage2 (one LDS atomic per record)
    for (int i = tid; i < total; i += 512) {
        int rec = stage[i];
        int p = atomicAdd(&lcur[(rec >> 17) & 127], 1);
        stage2[p] = rec & 0x1FFFF;
    }
    __syncthreads();
    if (tid < 128) {
        for (int k = val; k < padded; k++) stage2[lbase[tid] + k] = N_NODES; // zero row
    }
    __syncthreads();
    // ---- coalesced writeout
    int binpad = wtot2[0] + wtot2[1];
    int4* es4 = (int4*)(esrc + base);
    int b4 = binpad >> 2;
    for (int i4 = tid; i4 < b4; i4 += 512) {
        int i = i4 << 2;
        es4[i4] = make_int4(stage2[i], stage2[i + 1], stage2[i + 2], stage2[i + 3]);
    }
    // ---- per-node segment max (4 independent gathers/step; sentinel pads)
    float4 e4 = make_float4(0.f, 0.f, 0.f, 0.f);
    if (tid < 128) {
        int nrel = (sub << 7) + tid;
        int node = g * NSLICE + nrel;
        int lb = lbase[tid];
        float4 m = make_float4(-3e38f, -3e38f, -3e38f, -3e38f);
        for (int k = 0; k < padded; k += 4) {
            int s0 = stage2[lb + k], s1 = stage2[lb + k + 1];
            int s2 = stage2[lb + k + 2], s3 = stage2[lb + k + 3];
            float4 a0 = ((const float4*)s_src)[s0];
            float4 a1 = ((const float4*)s_src)[s1];
            float4 a2 = ((const float4*)s_src)[s2];
            float4 a3 = ((const float4*)s_src)[s3];
            m.x = fmaxf(fmaxf(m.x, a0.x), fmaxf(fmaxf(a1.x, a2.x), a3.x));
            m.y = fmaxf(fmaxf(m.y, a0.y), fmaxf(fmaxf(a1.y, a2.y), a3.y));
            m.z = fmaxf(fmaxf(m.z, a0.z), fmaxf(fmaxf(a1.z, a2.z), a3.z));
            m.w = fmaxf(fmaxf(m.w, a0.w), fmaxf(fmaxf(a1.w, a2.w), a3.w));
        }
        if (nrel < NSLICE) {
            float4 d = ((const float4*)s_dst)[node];
            float x;
            x = m.x + d.x; x = x > 0.f ? x : NEG_SLOPE * x; e4.x = __expf(x - EXP_SHIFT);
            x = m.y + d.y; x = x > 0.f ? x : NEG_SLOPE * x; e4.y = __expf(x - EXP_SHIFT);
            x = m.z + d.z; x = x > 0.f ? x : NEG_SLOPE * x; e4.z = __expf(x - EXP_SHIFT);
            x = m.w + d.w; x = x > 0.f ? x : NEG_SLOPE * x; e4.w = __expf(x - EXP_SHIFT);
            ((float4*)expv)[node] = e4;
        }
    }
    // ---- partial softmax denominator
    int lane = tid & 63, wv = tid >> 6;
#pragma unroll
    for (int off = 32; off; off >>= 1) {
        e4.x += __shfl_xor(e4.x, off);
        e4.y += __shfl_xor(e4.y, off);
        e4.z += __shfl_xor(e4.z, off);
        e4.w += __shfl_xor(e4.w, off);
    }
    if (lane == 0) { sred[wv][0] = e4.x; sred[wv][1] = e4.y; sred[wv][2] = e4.z; sred[wv][3] = e4.w; }
    __syncthreads();
    if (tid < 4) {
        float s = 0.f;
#pragma unroll
        for (int i = 0; i < 8; i++) s += sred[i][tid];
        atomicAdd(&S[tid], s);
    }
}

// ---------------- aggregate: one wave per node; scalar walk; deg is x4-padded
__global__ __launch_bounds__(256) void k_agg(const unsigned int* __restrict__ Whb32,
                                             const int* __restrict__ esrc,
                                             const int* __restrict__ start,
                                             const int* __restrict__ cnt,
                                             const float* __restrict__ expv,
                                             const float* __restrict__ S,
                                             float* __restrict__ out) {
    int node = (blockIdx.x * 256 + threadIdx.x) >> 6;
    if (node >= N_NODES) return;
    int lane = threadIdx.x & 63;
    int base = __builtin_amdgcn_readfirstlane(start[node]);
    int deg  = __builtin_amdgcn_readfirstlane(cnt[node]);
    const unsigned int* Wl = Whb32 + lane;
    float accx = 0.f, accy = 0.f;
    int i = 0;
    for (; i + 16 <= deg; i += 16) {
        unsigned int v[16];
#pragma unroll
        for (int j = 0; j < 16; j++) {
            int s = esrc[base + i + j];
            v[j] = Wl[(size_t)s * 64];
        }
#pragma unroll
        for (int j = 0; j < 16; j++) {
            accx += __uint_as_float(v[j] << 16);
            accy += __uint_as_float(v[j] & 0xffff0000u);
        }
    }
    for (; i < deg; i += 4) {
        unsigned int v[4];
#pragma unroll
        for (int j = 0; j < 4; j++) {
            int s = esrc[base + i + j];
            v[j] = Wl[(size_t)s * 64];
        }
#pragma unroll
        for (int j = 0; j < 4; j++) {
            accx += __uint_as_float(v[j] << 16);
            accy += __uint_as_float(v[j] & 0xffff0000u);
        }
    }
    int head = lane >> 4;
    float attn = expv[node * 4 + head] / S[head];
    ((float2*)out)[(size_t)node * 64 + lane] = make_float2(accx * attn, accy * attn);
}

extern "C" void kernel_launch(void* const* d_in, const int* in_sizes, int n_in,
                              void* d_out, int out_size, void* d_ws, size_t ws_size,
                              hipStream_t stream) {
    const float* h  = (const float*)d_in[0];
    const int*   ei = (const int*)d_in[1];
    const float* W  = (const float*)d_in[2];
    const float* a  = (const float*)d_in[3];
    float* out = (float*)d_out;

    char* ws = (char*)d_ws;
    unsigned short* Whb = (unsigned short*)(ws);   // 25,600,256 (100001 rows bf16)
    float* s_src = (float*)(ws + 25600256);        //  1,600,016 (incl sentinel row)
    float* s_dst = (float*)(ws + 27200272);        //  1,600,000
    float* expv  = (float*)(ws + 28800272);        //  1,600,000
    int*   cnt   = (int*)  (ws + 30400272);        //    400,000
    int*   start = (int*)  (ws + 30800272);        //    400,000
    float* S     = (float*)(ws + 31200272);        //         16 ┐ one
    int*   bcnt  = (int*)  (ws + 31200288);        //         32 ┘ memset
    int*   buck  = (int*)  (ws + 31200320);        //  6,720,000 (8 * 210000 * 4)
    int*   esrc  = (int*)  (ws + 37920320);        //  9,633,792 (784 * 3072 * 4)
    unsigned short* Wt = (unsigned short*)(ws + 47554112); // 32,768
                                                   // total 47,586,880 <= proven ws

    hipMemsetAsync(S, 0, 48, stream);              // S + bcnt
    k_prep<<<32, 256, 0, stream>>>(W, Wt, s_src);
    k_classify<<<(N_EDGES / 4 + 255) / 256, 256, 0, stream>>>(ei, bcnt, buck);
    k_gemm<<<782, 512, 0, stream>>>(h, Wt, a, Whb, s_src, s_dst);
    k_bin<<<8 * NBIN, 512, 0, stream>>>(bcnt, buck, s_src, s_dst,
                                        esrc, cnt, start, expv, S);
    k_agg<<<25000, 256, 0, stream>>>((const unsigned int*)Whb, esrc, start, cnt, expv, S, out);
}